// Round 3
// baseline (2187.713 us; speedup 1.0000x reference)
//
#include <hip/hip_runtime.h>
#include <hip/hip_cooperative_groups.h>

namespace cg = cooperative_groups;

typedef unsigned short u16;
typedef unsigned int   u32;
typedef short s16x8 __attribute__((ext_vector_type(8)));   // 8 bf16 lanes for MFMA
typedef float f32x4 __attribute__((ext_vector_type(4)));

// ---- bf16 helpers (store with round-to-nearest-even) ----
static __device__ __forceinline__ float bf2f(u16 v){ return __uint_as_float(((u32)v)<<16); }
static __device__ __forceinline__ u16 f2bf(float f){
  u32 u = __float_as_uint(f);
  u32 r = (u + 0x7fffu + ((u>>16)&1u)) >> 16;
  return (u16)r;
}
static __device__ __forceinline__ float cvt(float v){ return v; }
static __device__ __forceinline__ float cvt(u16 v){ return bf2f(v); }
static __device__ __forceinline__ void stv(float* p, float v){ *p = v; }
static __device__ __forceinline__ void stv(u16* p, float v){ *p = f2bf(v); }

static __device__ __forceinline__ void ld2(const float* p, float& a, float& b){
  float2 t = *(const float2*)p; a=t.x; b=t.y;
}
static __device__ __forceinline__ void ld2(const u16* p, float& a, float& b){
  u32 t = *(const u32*)p; a = __uint_as_float(t<<16); b = __uint_as_float(t & 0xffff0000u);
}
static __device__ __forceinline__ void st2(float* p, float a, float b){
  float2 t; t.x=a; t.y=b; *(float2*)p = t;
}
static __device__ __forceinline__ void st2(u16* p, float a, float b){
  *(u32*)p = ((u32)f2bf(a)) | (((u32)f2bf(b))<<16);
}

// ---------------- RMSNorm: O = X / rms(X) * scale, vectorized 2-wide ----------------
template<typename TI, typename TO>
__global__ __launch_bounds__(256) void rms_k(const TI* __restrict__ X,
                                             const float* __restrict__ scale,
                                             TO* __restrict__ O)
{
  int row = blockIdx.x*4 + (threadIdx.x>>6);
  int lane = threadIdx.x&63;
  const TI* xr = X + (size_t)row*384;
  float v[6]; float ss = 0.f;
#pragma unroll
  for(int i=0;i<3;i++){
    ld2(xr + 2*lane + 128*i, v[2*i], v[2*i+1]);
    ss += v[2*i]*v[2*i] + v[2*i+1]*v[2*i+1];
  }
#pragma unroll
  for(int off=32; off>0; off>>=1) ss += __shfl_down(ss, off, 64);
  ss = __shfl(ss, 0, 64);
  float r = rsqrtf(ss*(1.0f/384.0f)+1e-6f);
  TO* orow = O + (size_t)row*384;
#pragma unroll
  for(int i=0;i<3;i++){
    int c = 2*lane + 128*i;
    st2(orow + c, v[2*i]*r*scale[c], v[2*i+1]*r*scale[c+1]);
  }
}

// ---------------- transpose + cast fp32 -> bf16: Out[c][r] = (r<Rr ? In[r][c] : 0) ----------------
__global__ __launch_bounds__(256) void tcast_k(const float* __restrict__ In, long isz,
                                               u16* __restrict__ Out, long osz,
                                               int Rr, int Cc, int ldo)
{
  __shared__ float t[32][33];
  const int z = blockIdx.z;
  const float* I = In + (long)z*isz;
  u16* Oz = Out + (long)z*osz;
  const int r0 = blockIdx.x*32, c0 = blockIdx.y*32;
  const int tx = threadIdx.x&31, ty = threadIdx.x>>5;
#pragma unroll
  for(int rr=ty; rr<32; rr+=8){
    int r = r0+rr, c = c0+tx;
    t[rr][tx] = (r<Rr && c<Cc) ? I[(size_t)r*Cc + c] : 0.f;
  }
  __syncthreads();
#pragma unroll
  for(int cc=ty; cc<32; cc+=8){
    int c = c0+cc, r = r0+tx;
    if(c<Cc && r<ldo) Oz[(size_t)c*ldo + r] = f2bf(t[tx][cc]);
  }
}

// ---------------- bf16 MFMA GEMM: C = A[M,K] @ Bt[N,K]^T (+ beta*R + bias, relu) ----------------
template<typename TC, typename TR>
__global__ __launch_bounds__(256,4) void mgemm_k(
    const u16* __restrict__ A, int lda, long asz,
    const u16* __restrict__ Bt, int ldb, long bsz,
    TC* __restrict__ C, long csz, long cs_hi, int cs_lo,
    const TR* __restrict__ R, long rsz,
    const float* __restrict__ bias,
    int M, int N, int Nstore, int K, float beta, int relu)
{
  __shared__ __align__(16) u16 As[128*40];
  __shared__ __align__(16) u16 Bs[64*40];
  const int z = blockIdx.z;
  const u16* Az = A + (long)z*asz;
  const u16* Bz = Bt + (long)z*bsz;
  const int m0 = blockIdx.x*128, n0 = blockIdx.y*64;
  const int tid = threadIdx.x;
  const int w = tid>>6, lane = tid&63;
  const int g4 = lane>>4, l16 = lane&15;
  const int wr = w>>1, wc = w&1;
  const int arow = tid>>2, akc = (tid&3)*8;

  const u16* gA0 = Az + (size_t)(m0+arow)*lda + akc;
  const u16* gA1 = Az + (size_t)(m0+64+arow)*lda + akc;
  const bool bok = (n0 + arow) < N;
  const u16* gB  = Bz + (size_t)(bok ? (n0+arow) : 0)*ldb + akc;
  uint4* dA0 = (uint4*)&As[arow*40 + akc];
  uint4* dA1 = (uint4*)&As[(64+arow)*40 + akc];
  uint4* dB  = (uint4*)&Bs[arow*40 + akc];
  if(!bok){ *dB = make_uint4(0,0,0,0); }

  f32x4 fz = {0.f,0.f,0.f,0.f};
  f32x4 acc[4][2];
#pragma unroll
  for(int i=0;i<4;i++)
#pragma unroll
    for(int j=0;j<2;j++) acc[i][j]=fz;

  for(int k0=0;k0<K;k0+=32){
    *dA0 = *(const uint4*)gA0;  gA0 += 32;
    *dA1 = *(const uint4*)gA1;  gA1 += 32;
    if(bok){ *dB = *(const uint4*)gB; gB += 32; }
    __syncthreads();
    s16x8 av[4], bv[2];
#pragma unroll
    for(int mf=0;mf<4;mf++)
      av[mf] = *(const s16x8*)&As[(wr*64 + mf*16 + l16)*40 + g4*8];
#pragma unroll
    for(int nf=0;nf<2;nf++)
      bv[nf] = *(const s16x8*)&Bs[(wc*32 + nf*16 + l16)*40 + g4*8];
#pragma unroll
    for(int mf=0;mf<4;mf++)
#pragma unroll
      for(int nf=0;nf<2;nf++)
        acc[mf][nf] = __builtin_amdgcn_mfma_f32_16x16x32_bf16(av[mf], bv[nf], acc[mf][nf], 0,0,0);
    __syncthreads();
  }
#pragma unroll
  for(int mf=0;mf<4;mf++)
#pragma unroll
    for(int i=0;i<4;i++){
      int m = m0 + wr*64 + mf*16 + g4*4 + i;
      long rowoff = (long)(m>>8)*cs_hi + (long)(m&255)*cs_lo;
#pragma unroll
      for(int nf=0;nf<2;nf++){
        int n = n0 + wc*32 + nf*16 + l16;
        if(n < Nstore){
          float v = 0.f;
          if(n < N){
            v = acc[mf][nf][i];
            if(R)    v += beta*cvt(R[rowoff + (long)z*rsz + n]);
            if(bias) v += bias[n];
            if(relu) v  = fmaxf(v, 0.f);
          }
          stv(C + (long)z*csz + rowoff + n, v);
        }
      }
    }
}

// ---------------- MFMA causal flash attention: one block per (b,h), T=256, HS=64 ----------------
// QKV packed [B,H,{q,k,v},T,64] bf16: Qb = QKV + bh*49152, K at +16384, V at +32768.
__global__ __launch_bounds__(256,2) void mattn_k(const u16* __restrict__ QKV,
                                                 u16* __restrict__ O)
{
  __shared__ __align__(16) u16 Ks[64*64];    // [s][d], byte = s*128+2d ^ ((s&7)<<4)
  __shared__ __align__(16) u16 Vts[64*64];   // [d][s], byte = d*128+2s ^ ((d&7)<<4)
  __shared__ __align__(16) u16 Ps[4*4096];   // per-wave [m][s], byte = m*128+2s ^ ((m&7)<<4)
  const int bh = blockIdx.x;
  const int b = bh/6, h = bh - b*6;
  const u16* Qb = QKV + (size_t)bh*49152;
  const u16* Kb = Qb + 16384;
  const u16* Vb = Qb + 32768;
  const int tid = threadIdx.x;
  const int w = tid>>6, lane = tid&63;
  const int g4 = lane>>4, l16 = lane&15;
  char* PB = (char*)&Ps[w*4096];
  const int swz = (l16&7)<<4;

  s16x8 qf[4][2];
#pragma unroll
  for(int mi=0;mi<4;mi++)
#pragma unroll
    for(int ks=0;ks<2;ks++)
      qf[mi][ks] = *(const s16x8*)(Qb + (size_t)(w*64 + mi*16 + l16)*64 + ks*32 + g4*8);

  f32x4 fzv = {0.f,0.f,0.f,0.f};
  f32x4 o[4][4];
#pragma unroll
  for(int mf=0;mf<4;mf++)
#pragma unroll
    for(int df=0;df<4;df++) o[mf][df]=fzv;
  float mrun[4], lrun[4];
#pragma unroll
  for(int mi=0;mi<4;mi++){ mrun[mi]=-1e30f; lrun[mi]=0.f; }

  for(int st=0; st<4; ++st){
    if(st) __syncthreads();
#pragma unroll
    for(int it=0; it<2; ++it){
      int c = tid + 256*it;
      int s = c>>3, d0 = (c&7)*8;
      uint4 ld = *(const uint4*)(Kb + (size_t)(st*64+s)*64 + d0);
      int byte = s*128 + d0*2; byte ^= (s&7)<<4;
      *(uint4*)((char*)Ks + byte) = ld;
    }
#pragma unroll
    for(int it=0; it<2; ++it){
      int c = tid + 256*it;
      int s = c&63, d0 = (c>>6)*8;
      uint4 ld = *(const uint4*)(Vb + (size_t)(st*64+s)*64 + d0);
#pragma unroll
      for(int jj=0; jj<4; ++jj){
        u32 ww = (jj==0)?ld.x:(jj==1)?ld.y:(jj==2)?ld.z:ld.w;
        int d = d0 + 2*jj;
        int byte0 = d*128 + s*2;     byte0 ^= (d&7)<<4;
        int byte1 = (d+1)*128 + s*2; byte1 ^= ((d+1)&7)<<4;
        *(u16*)((char*)Vts + byte0) = (u16)(ww & 0xffffu);
        *(u16*)((char*)Vts + byte1) = (u16)(ww >> 16);
      }
    }
    __syncthreads();
    if(w < st) continue;

    f32x4 sc[4][4];
#pragma unroll
    for(int sf=0; sf<4; ++sf){
      int row = sf*16 + l16;
      s16x8 kf0 = *(const s16x8*)((char*)Ks + ((row*128 + g4*16) ^ swz));
      s16x8 kf1 = *(const s16x8*)((char*)Ks + ((row*128 + 64 + g4*16) ^ swz));
#pragma unroll
      for(int mi=0; mi<4; ++mi){
        f32x4 t = __builtin_amdgcn_mfma_f32_16x16x32_bf16(kf0, qf[mi][0], fzv, 0,0,0);
        sc[sf][mi] = __builtin_amdgcn_mfma_f32_16x16x32_bf16(kf1, qf[mi][1], t, 0,0,0);
      }
    }
    float alpha[4];
#pragma unroll
    for(int mi=0; mi<4; ++mi){
      int mloc = mi*16 + l16;
      float rmax = -3.0e38f;
#pragma unroll
      for(int sf=0; sf<4; ++sf)
#pragma unroll
        for(int i=0;i<4;i++){
          float vv = sc[sf][mi][i]*0.125f;
          if(st==w && (sf*16 + g4*4 + i) > mloc) vv = -1e30f;
          sc[sf][mi][i] = vv;
          rmax = fmaxf(rmax, vv);
        }
      rmax = fmaxf(rmax, __shfl_xor(rmax, 16, 64));
      rmax = fmaxf(rmax, __shfl_xor(rmax, 32, 64));
      float mnew = fmaxf(mrun[mi], rmax);
      float al = __expf(mrun[mi] - mnew);
      mrun[mi] = mnew;
      float ls = 0.f;
#pragma unroll
      for(int sf=0; sf<4; ++sf){
        float p0 = __expf(sc[sf][mi][0]-mnew);
        float p1 = __expf(sc[sf][mi][1]-mnew);
        float p2 = __expf(sc[sf][mi][2]-mnew);
        float p3 = __expf(sc[sf][mi][3]-mnew);
        ls += p0+p1+p2+p3;
        ushort4 pk; pk.x=f2bf(p0); pk.y=f2bf(p1); pk.z=f2bf(p2); pk.w=f2bf(p3);
        int byte = mloc*128 + sf*32 + g4*8; byte ^= (l16&7)<<4;
        *(ushort4*)(PB + byte) = pk;
      }
      ls += __shfl_xor(ls, 16, 64);
      ls += __shfl_xor(ls, 32, 64);
      lrun[mi] = lrun[mi]*al + ls;
      alpha[mi] = al;
    }
#pragma unroll
    for(int mf=0; mf<4; ++mf)
#pragma unroll
      for(int i=0;i<4;i++){
        float at = __shfl(alpha[mf], g4*4 + i, 64);
#pragma unroll
        for(int df=0; df<4; ++df) o[mf][df][i] *= at;
      }
    s16x8 vbf[4][2];
#pragma unroll
    for(int df=0; df<4; ++df){
      int row = df*16 + l16;
      vbf[df][0] = *(const s16x8*)((char*)Vts + ((row*128 + g4*16) ^ swz));
      vbf[df][1] = *(const s16x8*)((char*)Vts + ((row*128 + 64 + g4*16) ^ swz));
    }
#pragma unroll
    for(int mf=0; mf<4; ++mf){
      int row = mf*16 + l16;
      s16x8 pa0 = *(const s16x8*)(PB + ((row*128 + g4*16) ^ swz));
      s16x8 pa1 = *(const s16x8*)(PB + ((row*128 + 64 + g4*16) ^ swz));
#pragma unroll
      for(int df=0; df<4; ++df){
        f32x4 t = __builtin_amdgcn_mfma_f32_16x16x32_bf16(pa0, vbf[df][0], o[mf][df], 0,0,0);
        o[mf][df] = __builtin_amdgcn_mfma_f32_16x16x32_bf16(pa1, vbf[df][1], t, 0,0,0);
      }
    }
  }
#pragma unroll
  for(int mf=0; mf<4; ++mf)
#pragma unroll
    for(int i=0;i<4;i++){
      float lt = __shfl(lrun[mf], g4*4 + i, 64);
      float rl = 1.f/lt;
      u16* orow = O + ((size_t)(b*256 + w*64 + mf*16 + g4*4 + i))*384 + h*64;
#pragma unroll
      for(int df=0; df<4; ++df)
        orow[df*16 + l16] = f2bf(o[mf][df][i]*rl);
    }
}

// ---------------- cooperative Newton-Schulz, panel formulation, bf16x2 MFMA ----------------
// 48 blocks = 24 col-panels (16 wide) x 2 z. One grid.sync per iteration.
// X kept as bf16 hi/lo pairs in BOTH row-major (X) and transposed (XT) layouts,
// double-buffered (set 0/1). Thin MM: D[384x16] = A[384x384] * B[384x16],
// A read row-major from global (X or XT), B read as B^T[16][384] (global XT rows
// for MM1, LDS panels otherwise). bf16x2: 3 MFMA passes (hi*hi, hi*lo, lo*hi).
#define NS_BSTR 396   // LDS B^T row stride in u16 (mod-32-dword = 6 -> <=2-way banks)

template<int BSTRIDE>
static __device__ __forceinline__ void thin_mm(
    const u16* __restrict__ Ahi, const u16* __restrict__ Alo,
    const u16* __restrict__ Bhi, const u16* __restrict__ Blo,
    int w, int lane, f32x4 acc[6])
{
  const int g4 = lane>>4, l16 = lane&15;
  f32x4 fz = {0.f,0.f,0.f,0.f};
#pragma unroll
  for(int i=0;i<6;i++) acc[i]=fz;
  for(int ks=0; ks<12; ++ks){
    const int kofs = ks*32 + g4*8;
    s16x8 bh, bl;
    if(BSTRIDE==384){
      bh = *(const s16x8*)&Bhi[l16*384 + kofs];
      bl = *(const s16x8*)&Blo[l16*384 + kofs];
    } else {
      ((ushort4*)&bh)[0] = *(const ushort4*)&Bhi[l16*BSTRIDE + kofs];
      ((ushort4*)&bh)[1] = *(const ushort4*)&Bhi[l16*BSTRIDE + kofs + 4];
      ((ushort4*)&bl)[0] = *(const ushort4*)&Blo[l16*BSTRIDE + kofs];
      ((ushort4*)&bl)[1] = *(const ushort4*)&Blo[l16*BSTRIDE + kofs + 4];
    }
#pragma unroll
    for(int mf=0; mf<6; ++mf){
      const int m = 96*w + mf*16 + l16;
      s16x8 ah = *(const s16x8*)&Ahi[m*384 + kofs];
      s16x8 al = *(const s16x8*)&Alo[m*384 + kofs];
      acc[mf] = __builtin_amdgcn_mfma_f32_16x16x32_bf16(ah, bh, acc[mf],0,0,0);
      acc[mf] = __builtin_amdgcn_mfma_f32_16x16x32_bf16(ah, bl, acc[mf],0,0,0);
      acc[mf] = __builtin_amdgcn_mfma_f32_16x16x32_bf16(al, bh, acc[mf],0,0,0);
    }
  }
}

__global__ __launch_bounds__(256,1) void ns2_k(const float* __restrict__ W0,
                                               const float* __restrict__ W1,
                                               u16* __restrict__ XB,
                                               u16* __restrict__ QT)
{
  cg::grid_group grid = cg::this_grid();
  __shared__ __align__(16) u16 bGh[16*NS_BSTR], bGl[16*NS_BSTR];
  __shared__ __align__(16) u16 bUh[16*NS_BSTR], bUl[16*NS_BSTR];
  __shared__ float red[256];
  const int blk = blockIdx.x;
  const int z = blk/24, p = blk%24, cp0 = p*16;
  const int tid = threadIdx.x;
  const int w = tid>>6, lane = tid&63;
  const int g4 = lane>>4, l16 = lane&15;
  const float* W = z ? W1 : W0;
  const int zo = z*147456;

  // Frobenius norm, redundant per block (identical order -> identical result)
  float s = 0.f;
  for(int i=tid; i<147456; i+=256){ float v = W[i]; s += v*v; }
  red[tid] = s; __syncthreads();
  for(int off=128; off>0; off>>=1){ if(tid<off) red[tid]+=red[tid+off]; __syncthreads(); }
  const float inv = rsqrtf(red[0]);

  // init X = W/||W||_F into set 0 (both layouts, hi/lo)
  {
    u16* xh = XB + zo;            u16* xl = XB + 294912 + zo;
    u16* th = XB + 589824 + zo;   u16* tl = XB + 884736 + zo;
    for(int idx=tid; idx<6144; idx+=256){
      int r = idx>>4, c = cp0 + (idx&15);
      float v = W[r*384 + c]*inv;
      u16 hh = f2bf(v); u16 ll = f2bf(v - bf2f(hh));
      xh[r*384+c]=hh; xl[r*384+c]=ll; th[c*384+r]=hh; tl[c*384+r]=ll;
    }
  }
  grid.sync();

  f32x4 acc[6];
  for(int it=0; it<16; ++it){
    const bool quint = (it < 11);
    const int rs = (it&1), ws2 = rs^1;
    const u16* xh = XB + rs*1179648 + zo;
    const u16* xl = XB + rs*1179648 + 294912 + zo;
    const u16* th = XB + rs*1179648 + 589824 + zo;
    const u16* tl = XB + rs*1179648 + 884736 + zo;

    // MM1: G_cp = X^T X_cp   (A = XT global, B^T = XT rows cp0.. global)
    thin_mm<384>(th, tl, th + cp0*384, tl + cp0*384, w, lane, acc);
#pragma unroll
    for(int mf=0; mf<6; ++mf){
      int k0 = 96*w + mf*16 + g4*4;
      ushort4 h4, l4;
#pragma unroll
      for(int i=0;i<4;i++){
        float v = acc[mf][i];
        if(!quint) v = -0.5f*v + ((k0+i)==(cp0+l16) ? 1.5f : 0.f);  // cubic: M directly
        u16 hh = f2bf(v); u16 ll = f2bf(v - bf2f(hh));
        ((u16*)&h4)[i]=hh; ((u16*)&l4)[i]=ll;
      }
      *(ushort4*)&bGh[l16*NS_BSTR + k0] = h4;
      *(ushort4*)&bGl[l16*NS_BSTR + k0] = l4;
    }
    __syncthreads();

    if(quint){
      // MM2: U = X * G_cp
      thin_mm<NS_BSTR>(xh, xl, bGh, bGl, w, lane, acc);
#pragma unroll
      for(int mf=0; mf<6; ++mf){
        int k0 = 96*w + mf*16 + g4*4;
        ushort4 h4, l4;
#pragma unroll
        for(int i=0;i<4;i++){
          float v = acc[mf][i];
          u16 hh = f2bf(v); u16 ll = f2bf(v - bf2f(hh));
          ((u16*)&h4)[i]=hh; ((u16*)&l4)[i]=ll;
        }
        *(ushort4*)&bUh[l16*NS_BSTR + k0] = h4;
        *(ushort4*)&bUl[l16*NS_BSTR + k0] = l4;
      }
      __syncthreads();
      // MM3: T = X^T * U  (= G^2 col-panel)
      thin_mm<NS_BSTR>(th, tl, bUh, bUl, w, lane, acc);
      __syncthreads();               // all bU reads done before overwrite with M
#pragma unroll
      for(int mf=0; mf<6; ++mf){
        int k0 = 96*w + mf*16 + g4*4;
        ushort4 gh = *(const ushort4*)&bGh[l16*NS_BSTR + k0];
        ushort4 gl = *(const ushort4*)&bGl[l16*NS_BSTR + k0];
        ushort4 h4, l4;
#pragma unroll
        for(int i=0;i<4;i++){
          float g = bf2f(((u16*)&gh)[i]) + bf2f(((u16*)&gl)[i]);
          float v = fmaf(-4.7750f, g, 2.0315f*acc[mf][i])
                  + ((k0+i)==(cp0+l16) ? 3.4445f : 0.f);
          u16 hh = f2bf(v); u16 ll = f2bf(v - bf2f(hh));
          ((u16*)&h4)[i]=hh; ((u16*)&l4)[i]=ll;
        }
        *(ushort4*)&bUh[l16*NS_BSTR + k0] = h4;
        *(ushort4*)&bUl[l16*NS_BSTR + k0] = l4;
      }
      __syncthreads();
      // MM4: Xn = X * M
      thin_mm<NS_BSTR>(xh, xl, bUh, bUl, w, lane, acc);
    } else {
      // cubic: Xn = X * (1.5 I - 0.5 G)   (M already in bG)
      thin_mm<NS_BSTR>(xh, xl, bGh, bGl, w, lane, acc);
    }

    if(it==15){
      // final: QT[z][col][row] = bf16(Q[row][col])
#pragma unroll
      for(int mf=0; mf<6; ++mf){
        int r0 = 96*w + mf*16 + g4*4;
        ushort4 h4;
#pragma unroll
        for(int i=0;i<4;i++) ((u16*)&h4)[i] = f2bf(acc[mf][i]);
        *(ushort4*)&QT[zo + (cp0+l16)*384 + r0] = h4;
      }
    } else {
      u16* nxh = XB + ws2*1179648 + zo;
      u16* nxl = XB + ws2*1179648 + 294912 + zo;
      u16* nth = XB + ws2*1179648 + 589824 + zo;
      u16* ntl = XB + ws2*1179648 + 884736 + zo;
#pragma unroll
      for(int mf=0; mf<6; ++mf){
        int r0 = 96*w + mf*16 + g4*4;
        ushort4 h4, l4;
#pragma unroll
        for(int i=0;i<4;i++){
          float v = acc[mf][i];
          u16 hh = f2bf(v); u16 ll = f2bf(v - bf2f(hh));
          ((u16*)&h4)[i]=hh; ((u16*)&l4)[i]=ll;
        }
        *(ushort4*)&nth[(cp0+l16)*384 + r0] = h4;
        *(ushort4*)&ntl[(cp0+l16)*384 + r0] = l4;
#pragma unroll
        for(int i=0;i<4;i++){
          nxh[(r0+i)*384 + cp0+l16] = ((u16*)&h4)[i];
          nxl[(r0+i)*384 + cp0+l16] = ((u16*)&l4)[i];
        }
      }
      grid.sync();
    }
  }
}

// ---------------- host-side orchestration ----------------
extern "C" void kernel_launch(void* const* d_in, const int* in_sizes, int n_in,
                              void* d_out, int out_size, void* d_ws, size_t ws_size,
                              hipStream_t stream)
{
  const float* x      = (const float*)d_in[0];
  const float* Wq     = (const float*)d_in[1];
  const float* Wk     = (const float*)d_in[2];
  const float* Wv     = (const float*)d_in[3];
  const float* Wp     = (const float*)d_in[4];
  const float* bp     = (const float*)d_in[5];
  const float* scale1 = (const float*)d_in[6];
  const float* scale2 = (const float*)d_in[7];
  const float* W1     = (const float*)d_in[8];
  const float* b1     = (const float*)d_in[9];
  const float* W2     = (const float*)d_in[10];
  const float* b2     = (const float*)d_in[11];
  const float* Wo_in  = (const float*)d_in[12];
  const float* Wo_out = (const float*)d_in[13];

  // ---- workspace layout ----
  char* ws = (char*)d_ws;
  u16* XB   = (u16*)(ws + 0);                 // NS X buffers: 2 sets x {Xhi,Xlo,XThi,XTlo} x 2z = 4718592 B
  u16* Wqkv = (u16*)(ws + 4719104L);          // [h][{q,k,v}][64][384] bf16
  u16* WpT  = (u16*)(ws + 5603840L);          // [384][384]
  u16* W1T  = (u16*)(ws + 5898752L);          // [307][384]
  u16* W2T  = (u16*)(ws + 6134528L);          // [384][320] (k-padded with zeros)
  u16* QT   = (u16*)(ws + 6380288L);          // orth(Wo_in)^T, orth(Wo_out)^T bf16
  u16* h1b  = (u16*)(ws + 8388608L);          // S0: h1 -> h6                (48 MB)
  u16* qkvb = (u16*)(ws + 58720256L);         // S1-S3: qkv packed -> h2/h3/h4 (144 MB)
  u16* atb  = (u16*)(ws + 209715200L);        // S4: attn_cat -> h5 [65536][320]
  u16* h2b = qkvb;
  u16* h3b = qkvb + 25165824L;
  u16* h4b = qkvb + 50331648L;
  u16* h5b = atb;
  u16* h6b = h1b;

  // --- weight transpose+cast ---
  tcast_k<<<dim3(12, 2,6),256,0,stream>>>(Wq,24576L, Wqkv,        73728L, 384, 64,384);
  tcast_k<<<dim3(12, 2,6),256,0,stream>>>(Wk,24576L, Wqkv+24576L, 73728L, 384, 64,384);
  tcast_k<<<dim3(12, 2,6),256,0,stream>>>(Wv,24576L, Wqkv+49152L, 73728L, 384, 64,384);
  tcast_k<<<dim3(12,12,1),256,0,stream>>>(Wp,0L,     WpT,0L,     384,384,384);
  tcast_k<<<dim3(12,10,1),256,0,stream>>>(W1,0L,     W1T,0L,     384,307,384);
  tcast_k<<<dim3(10,12,1),256,0,stream>>>(W2,0L,     W2T,0L,     307,384,320);

  // --- orth via single cooperative panel-NS kernel (1 grid.sync/iter) ---
  {
    const float* a0 = Wo_in; const float* a1 = Wo_out;
    u16* px = XB; u16* pq = QT;
    void* nsargs[] = { (void*)&a0, (void*)&a1, (void*)&px, (void*)&pq };
    hipLaunchCooperativeKernel((const void*)&ns2_k, dim3(48), dim3(256),
                               nsargs, 0u, stream);
  }

  // --- main path: bf16 activations + MFMA throughout ---
  rms_k<float,u16><<<16384,256,0,stream>>>(x, scale1, h1b);
  mgemm_k<u16,float><<<dim3(512,1,18),256,0,stream>>>(
      h1b,384,0L,  Wqkv,384,24576L,
      qkvb,16384L,294912L,64,  (const float*)nullptr,0L, nullptr,
      65536,64,64,384, 0.f,0);
  mattn_k<<<1536,256,0,stream>>>(qkvb, atb);
  mgemm_k<u16,u16><<<dim3(512,6,1),256,0,stream>>>(
      atb,384,0L,  WpT,384,0L,
      h2b,0L,98304L,384,  h1b,0L, bp,
      65536,384,384,384, 1.f,0);
  rms_k<u16,u16><<<16384,256,0,stream>>>(h2b, scale2, h3b);
  mgemm_k<u16,float><<<dim3(512,6,1),256,0,stream>>>(
      h3b,384,0L,  QT,384,0L,
      h4b,0L,98304L,384,  (const float*)nullptr,0L, nullptr,
      65536,384,384,384, 0.f,0);
  mgemm_k<u16,float><<<dim3(512,5,1),256,0,stream>>>(
      h4b,384,0L,  W1T,384,0L,
      h5b,0L,81920L,320,  (const float*)nullptr,0L, b1,
      65536,307,320,384, 0.f,1);
  mgemm_k<u16,float><<<dim3(512,6,1),256,0,stream>>>(
      h5b,320,0L,  W2T,320,0L,
      h6b,0L,98304L,384,  (const float*)nullptr,0L, b2,
      65536,384,384,320, 0.f,0);
  mgemm_k<float,u16><<<dim3(512,6,1),256,0,stream>>>(
      h6b,384,0L,  QT+147456,384,0L,
      (float*)d_out,0L,98304L,384,  h6b,0L, nullptr,
      65536,384,384,384, 1.f,0);

  (void)in_sizes; (void)n_in; (void)ws_size; (void)out_size;
}

// Round 4
// 1594.738 us; speedup vs baseline: 1.3718x; 1.3718x over previous
//
#include <hip/hip_runtime.h>

typedef unsigned short u16;
typedef unsigned int   u32;
typedef short s16x8 __attribute__((ext_vector_type(8)));   // 8 bf16 lanes for MFMA
typedef float f32x4 __attribute__((ext_vector_type(4)));

// ---- bf16 helpers (store with round-to-nearest-even) ----
static __device__ __forceinline__ float bf2f(u16 v){ return __uint_as_float(((u32)v)<<16); }
static __device__ __forceinline__ u16 f2bf(float f){
  u32 u = __float_as_uint(f);
  u32 r = (u + 0x7fffu + ((u>>16)&1u)) >> 16;
  return (u16)r;
}
static __device__ __forceinline__ float cvt(float v){ return v; }
static __device__ __forceinline__ float cvt(u16 v){ return bf2f(v); }
static __device__ __forceinline__ void stv(float* p, float v){ *p = v; }
static __device__ __forceinline__ void stv(u16* p, float v){ *p = f2bf(v); }

static __device__ __forceinline__ void ld2(const float* p, float& a, float& b){
  float2 t = *(const float2*)p; a=t.x; b=t.y;
}
static __device__ __forceinline__ void ld2(const u16* p, float& a, float& b){
  u32 t = *(const u32*)p; a = __uint_as_float(t<<16); b = __uint_as_float(t & 0xffff0000u);
}
static __device__ __forceinline__ void st2(float* p, float a, float b){
  float2 t; t.x=a; t.y=b; *(float2*)p = t;
}
static __device__ __forceinline__ void st2(u16* p, float a, float b){
  *(u32*)p = ((u32)f2bf(a)) | (((u32)f2bf(b))<<16);
}

// ---------------- RMSNorm: O = X / rms(X) * scale, vectorized 2-wide ----------------
template<typename TI, typename TO>
__global__ __launch_bounds__(256) void rms_k(const TI* __restrict__ X,
                                             const float* __restrict__ scale,
                                             TO* __restrict__ O)
{
  int row = blockIdx.x*4 + (threadIdx.x>>6);
  int lane = threadIdx.x&63;
  const TI* xr = X + (size_t)row*384;
  float v[6]; float ss = 0.f;
#pragma unroll
  for(int i=0;i<3;i++){
    ld2(xr + 2*lane + 128*i, v[2*i], v[2*i+1]);
    ss += v[2*i]*v[2*i] + v[2*i+1]*v[2*i+1];
  }
#pragma unroll
  for(int off=32; off>0; off>>=1) ss += __shfl_down(ss, off, 64);
  ss = __shfl(ss, 0, 64);
  float r = rsqrtf(ss*(1.0f/384.0f)+1e-6f);
  TO* orow = O + (size_t)row*384;
#pragma unroll
  for(int i=0;i<3;i++){
    int c = 2*lane + 128*i;
    st2(orow + c, v[2*i]*r*scale[c], v[2*i+1]*r*scale[c+1]);
  }
}

// ---------------- transpose + cast fp32 -> bf16: Out[c][r] = (r<Rr ? In[r][c] : 0) ----------------
__global__ __launch_bounds__(256) void tcast_k(const float* __restrict__ In, long isz,
                                               u16* __restrict__ Out, long osz,
                                               int Rr, int Cc, int ldo)
{
  __shared__ float t[32][33];
  const int z = blockIdx.z;
  const float* I = In + (long)z*isz;
  u16* Oz = Out + (long)z*osz;
  const int r0 = blockIdx.x*32, c0 = blockIdx.y*32;
  const int tx = threadIdx.x&31, ty = threadIdx.x>>5;
#pragma unroll
  for(int rr=ty; rr<32; rr+=8){
    int r = r0+rr, c = c0+tx;
    t[rr][tx] = (r<Rr && c<Cc) ? I[(size_t)r*Cc + c] : 0.f;
  }
  __syncthreads();
#pragma unroll
  for(int cc=ty; cc<32; cc+=8){
    int c = c0+cc, r = r0+tx;
    if(c<Cc && r<ldo) Oz[(size_t)c*ldo + r] = f2bf(t[tx][cc]);
  }
}

// ---------------- bf16 MFMA GEMM: C = A[M,K] @ Bt[N,K]^T (+ beta*R + bias, relu) ----------------
template<typename TC, typename TR>
__global__ __launch_bounds__(256,4) void mgemm_k(
    const u16* __restrict__ A, int lda, long asz,
    const u16* __restrict__ Bt, int ldb, long bsz,
    TC* __restrict__ C, long csz, long cs_hi, int cs_lo,
    const TR* __restrict__ R, long rsz,
    const float* __restrict__ bias,
    int M, int N, int Nstore, int K, float beta, int relu)
{
  __shared__ __align__(16) u16 As[128*40];
  __shared__ __align__(16) u16 Bs[64*40];
  const int z = blockIdx.z;
  const u16* Az = A + (long)z*asz;
  const u16* Bz = Bt + (long)z*bsz;
  const int m0 = blockIdx.x*128, n0 = blockIdx.y*64;
  const int tid = threadIdx.x;
  const int w = tid>>6, lane = tid&63;
  const int g4 = lane>>4, l16 = lane&15;
  const int wr = w>>1, wc = w&1;
  const int arow = tid>>2, akc = (tid&3)*8;

  const u16* gA0 = Az + (size_t)(m0+arow)*lda + akc;
  const u16* gA1 = Az + (size_t)(m0+64+arow)*lda + akc;
  const bool bok = (n0 + arow) < N;
  const u16* gB  = Bz + (size_t)(bok ? (n0+arow) : 0)*ldb + akc;
  uint4* dA0 = (uint4*)&As[arow*40 + akc];
  uint4* dA1 = (uint4*)&As[(64+arow)*40 + akc];
  uint4* dB  = (uint4*)&Bs[arow*40 + akc];
  if(!bok){ *dB = make_uint4(0,0,0,0); }

  f32x4 fz = {0.f,0.f,0.f,0.f};
  f32x4 acc[4][2];
#pragma unroll
  for(int i=0;i<4;i++)
#pragma unroll
    for(int j=0;j<2;j++) acc[i][j]=fz;

  for(int k0=0;k0<K;k0+=32){
    *dA0 = *(const uint4*)gA0;  gA0 += 32;
    *dA1 = *(const uint4*)gA1;  gA1 += 32;
    if(bok){ *dB = *(const uint4*)gB; gB += 32; }
    __syncthreads();
    s16x8 av[4], bv[2];
#pragma unroll
    for(int mf=0;mf<4;mf++)
      av[mf] = *(const s16x8*)&As[(wr*64 + mf*16 + l16)*40 + g4*8];
#pragma unroll
    for(int nf=0;nf<2;nf++)
      bv[nf] = *(const s16x8*)&Bs[(wc*32 + nf*16 + l16)*40 + g4*8];
#pragma unroll
    for(int mf=0;mf<4;mf++)
#pragma unroll
      for(int nf=0;nf<2;nf++)
        acc[mf][nf] = __builtin_amdgcn_mfma_f32_16x16x32_bf16(av[mf], bv[nf], acc[mf][nf], 0,0,0);
    __syncthreads();
  }
#pragma unroll
  for(int mf=0;mf<4;mf++)
#pragma unroll
    for(int i=0;i<4;i++){
      int m = m0 + wr*64 + mf*16 + g4*4 + i;
      long rowoff = (long)(m>>8)*cs_hi + (long)(m&255)*cs_lo;
#pragma unroll
      for(int nf=0;nf<2;nf++){
        int n = n0 + wc*32 + nf*16 + l16;
        if(n < Nstore){
          float v = 0.f;
          if(n < N){
            v = acc[mf][nf][i];
            if(R)    v += beta*cvt(R[rowoff + (long)z*rsz + n]);
            if(bias) v += bias[n];
            if(relu) v  = fmaxf(v, 0.f);
          }
          stv(C + (long)z*csz + rowoff + n, v);
        }
      }
    }
}

// ---------------- MFMA causal flash attention: one block per (b,h), T=256, HS=64 ----------------
// QKV packed [B,H,{q,k,v},T,64] bf16: Qb = QKV + bh*49152, K at +16384, V at +32768.
__global__ __launch_bounds__(256,2) void mattn_k(const u16* __restrict__ QKV,
                                                 u16* __restrict__ O)
{
  __shared__ __align__(16) u16 Ks[64*64];    // [s][d], byte = s*128+2d ^ ((s&7)<<4)
  __shared__ __align__(16) u16 Vts[64*64];   // [d][s], byte = d*128+2s ^ ((d&7)<<4)
  __shared__ __align__(16) u16 Ps[4*4096];   // per-wave [m][s], byte = m*128+2s ^ ((m&7)<<4)
  const int bh = blockIdx.x;
  const int b = bh/6, h = bh - b*6;
  const u16* Qb = QKV + (size_t)bh*49152;
  const u16* Kb = Qb + 16384;
  const u16* Vb = Qb + 32768;
  const int tid = threadIdx.x;
  const int w = tid>>6, lane = tid&63;
  const int g4 = lane>>4, l16 = lane&15;
  char* PB = (char*)&Ps[w*4096];
  const int swz = (l16&7)<<4;

  s16x8 qf[4][2];
#pragma unroll
  for(int mi=0;mi<4;mi++)
#pragma unroll
    for(int ks=0;ks<2;ks++)
      qf[mi][ks] = *(const s16x8*)(Qb + (size_t)(w*64 + mi*16 + l16)*64 + ks*32 + g4*8);

  f32x4 fzv = {0.f,0.f,0.f,0.f};
  f32x4 o[4][4];
#pragma unroll
  for(int mf=0;mf<4;mf++)
#pragma unroll
    for(int df=0;df<4;df++) o[mf][df]=fzv;
  float mrun[4], lrun[4];
#pragma unroll
  for(int mi=0;mi<4;mi++){ mrun[mi]=-1e30f; lrun[mi]=0.f; }

  for(int st=0; st<4; ++st){
    if(st) __syncthreads();
#pragma unroll
    for(int it=0; it<2; ++it){
      int c = tid + 256*it;
      int s = c>>3, d0 = (c&7)*8;
      uint4 ld = *(const uint4*)(Kb + (size_t)(st*64+s)*64 + d0);
      int byte = s*128 + d0*2; byte ^= (s&7)<<4;
      *(uint4*)((char*)Ks + byte) = ld;
    }
#pragma unroll
    for(int it=0; it<2; ++it){
      int c = tid + 256*it;
      int s = c&63, d0 = (c>>6)*8;
      uint4 ld = *(const uint4*)(Vb + (size_t)(st*64+s)*64 + d0);
#pragma unroll
      for(int jj=0; jj<4; ++jj){
        u32 ww = (jj==0)?ld.x:(jj==1)?ld.y:(jj==2)?ld.z:ld.w;
        int d = d0 + 2*jj;
        int byte0 = d*128 + s*2;     byte0 ^= (d&7)<<4;
        int byte1 = (d+1)*128 + s*2; byte1 ^= ((d+1)&7)<<4;
        *(u16*)((char*)Vts + byte0) = (u16)(ww & 0xffffu);
        *(u16*)((char*)Vts + byte1) = (u16)(ww >> 16);
      }
    }
    __syncthreads();
    if(w < st) continue;

    f32x4 sc[4][4];
#pragma unroll
    for(int sf=0; sf<4; ++sf){
      int row = sf*16 + l16;
      s16x8 kf0 = *(const s16x8*)((char*)Ks + ((row*128 + g4*16) ^ swz));
      s16x8 kf1 = *(const s16x8*)((char*)Ks + ((row*128 + 64 + g4*16) ^ swz));
#pragma unroll
      for(int mi=0; mi<4; ++mi){
        f32x4 t = __builtin_amdgcn_mfma_f32_16x16x32_bf16(kf0, qf[mi][0], fzv, 0,0,0);
        sc[sf][mi] = __builtin_amdgcn_mfma_f32_16x16x32_bf16(kf1, qf[mi][1], t, 0,0,0);
      }
    }
    float alpha[4];
#pragma unroll
    for(int mi=0; mi<4; ++mi){
      int mloc = mi*16 + l16;
      float rmax = -3.0e38f;
#pragma unroll
      for(int sf=0; sf<4; ++sf)
#pragma unroll
        for(int i=0;i<4;i++){
          float vv = sc[sf][mi][i]*0.125f;
          if(st==w && (sf*16 + g4*4 + i) > mloc) vv = -1e30f;
          sc[sf][mi][i] = vv;
          rmax = fmaxf(rmax, vv);
        }
      rmax = fmaxf(rmax, __shfl_xor(rmax, 16, 64));
      rmax = fmaxf(rmax, __shfl_xor(rmax, 32, 64));
      float mnew = fmaxf(mrun[mi], rmax);
      float al = __expf(mrun[mi] - mnew);
      mrun[mi] = mnew;
      float ls = 0.f;
#pragma unroll
      for(int sf=0; sf<4; ++sf){
        float p0 = __expf(sc[sf][mi][0]-mnew);
        float p1 = __expf(sc[sf][mi][1]-mnew);
        float p2 = __expf(sc[sf][mi][2]-mnew);
        float p3 = __expf(sc[sf][mi][3]-mnew);
        ls += p0+p1+p2+p3;
        ushort4 pk; pk.x=f2bf(p0); pk.y=f2bf(p1); pk.z=f2bf(p2); pk.w=f2bf(p3);
        int byte = mloc*128 + sf*32 + g4*8; byte ^= (l16&7)<<4;
        *(ushort4*)(PB + byte) = pk;
      }
      ls += __shfl_xor(ls, 16, 64);
      ls += __shfl_xor(ls, 32, 64);
      lrun[mi] = lrun[mi]*al + ls;
      alpha[mi] = al;
    }
#pragma unroll
    for(int mf=0; mf<4; ++mf)
#pragma unroll
      for(int i=0;i<4;i++){
        float at = __shfl(alpha[mf], g4*4 + i, 64);
#pragma unroll
        for(int df=0; df<4; ++df) o[mf][df][i] *= at;
      }
    s16x8 vbf[4][2];
#pragma unroll
    for(int df=0; df<4; ++df){
      int row = df*16 + l16;
      vbf[df][0] = *(const s16x8*)((char*)Vts + ((row*128 + g4*16) ^ swz));
      vbf[df][1] = *(const s16x8*)((char*)Vts + ((row*128 + 64 + g4*16) ^ swz));
    }
#pragma unroll
    for(int mf=0; mf<4; ++mf){
      int row = mf*16 + l16;
      s16x8 pa0 = *(const s16x8*)(PB + ((row*128 + g4*16) ^ swz));
      s16x8 pa1 = *(const s16x8*)(PB + ((row*128 + 64 + g4*16) ^ swz));
#pragma unroll
      for(int df=0; df<4; ++df){
        f32x4 t = __builtin_amdgcn_mfma_f32_16x16x32_bf16(pa0, vbf[df][0], o[mf][df], 0,0,0);
        o[mf][df] = __builtin_amdgcn_mfma_f32_16x16x32_bf16(pa1, vbf[df][1], t, 0,0,0);
      }
    }
  }
#pragma unroll
  for(int mf=0; mf<4; ++mf)
#pragma unroll
    for(int i=0;i<4;i++){
      float lt = __shfl(lrun[mf], g4*4 + i, 64);
      float rl = 1.f/lt;
      u16* orow = O + ((size_t)(b*256 + w*64 + mf*16 + g4*4 + i))*384 + h*64;
#pragma unroll
      for(int df=0; df<4; ++df)
        orow[df*16 + l16] = f2bf(o[mf][df][i]*rl);
    }
}

// ================= Newton-Schulz orthogonalization, stream-ordered =================
// Chunk-packed global layouts per z per set (u16 element offsets):
//   XcA [24][384][16]: XcA[c][r][j]  = X[r][16c+j]   (A-chunks for A=X; B-panel source)
//   XTcA[24][384][16]: XTcA[c][r][j] = X[16c+j][r]   (A-chunks for A=XT)
// hi/lo bf16 pairs for each. Set stride 1179648 el, z stride 589824 el.
// nsit_k: 48 blocks (z,panel16) x 384 threads (6 waves x 4 row-tiles).
// Chained MMs per quintic iter: G=XT*Bp, U=X*G, T=XT*U, M=aI+bG+cT, Xn=X*M.
// LDS: A-chunk [384][24-stride] hi+lo (36864 B) + BT'[16][392] [n][k] hi+lo (25088 B).
// K-chunks of 16 use 16x16x32 MFMA with upper K-half zeroed in BOTH operands.

__global__ __launch_bounds__(256) void fpart_k(const float* __restrict__ W0,
                                               const float* __restrict__ W1,
                                               float* __restrict__ part)
{
  int b = blockIdx.x; int z = b/24, seg = b - z*24;
  const float* W = (z ? W1 : W0) + seg*6144;
  int tid = threadIdx.x;
  float s = 0.f;
  for(int i=tid;i<6144;i+=256){ float v=W[i]; s+=v*v; }
#pragma unroll
  for(int off=32; off>0; off>>=1) s += __shfl_down(s, off, 64);
  __shared__ float red[4];
  if((tid&63)==0) red[tid>>6]=s;
  __syncthreads();
  if(tid==0) part[b] = red[0]+red[1]+red[2]+red[3];
}

__global__ __launch_bounds__(64) void fcomb_k(const float* __restrict__ part,
                                              float* __restrict__ invb)
{
  int lane = threadIdx.x;
  float v = 0.f;
  if(lane < 24) v = part[lane];
  else if(lane >= 32 && lane < 56) v = part[lane - 8];
#pragma unroll
  for(int off=1; off<32; off<<=1) v += __shfl_xor(v, off, 64);
  if(lane==0)  invb[0] = rsqrtf(v);
  if(lane==32) invb[1] = rsqrtf(v);
}

__global__ __launch_bounds__(256) void nsinit_k(const float* __restrict__ W0,
                                                const float* __restrict__ W1,
                                                const float* __restrict__ invb,
                                                u16* __restrict__ XB)
{
  int b = blockIdx.x; int z = b/24, p = b - z*24, cp0 = p*16;
  const float* W = z ? W1 : W0;
  float inv = invb[z];
  u16* base = XB + (size_t)z*589824;
  u16* xh = base;            u16* xl = base + 147456;
  u16* th = base + 294912;   u16* tl = base + 442368;
  int tid = threadIdx.x;
  for(int idx=tid; idx<6144; idx+=256){
    int r = idx>>4, j = idx&15;
    float v = W[r*384 + cp0 + j]*inv;
    u16 hh = f2bf(v);
    xh[p*6144 + idx] = hh;
    xl[p*6144 + idx] = f2bf(v - bf2f(hh));
  }
  for(int idx=tid; idx<6144; idx+=256){
    int j = idx/384, r = idx - j*384;
    float v = W[(cp0+j)*384 + r]*inv;
    u16 hh = f2bf(v);
    th[p*6144 + r*16 + j] = hh;
    tl[p*6144 + r*16 + j] = f2bf(v - bf2f(hh));
  }
}

// thin chained MM: D[384x16] = A * B; A from chunk-packed global (staged via LDS ring),
// B from LDS BT'[n][k]. acc[tt] = rows 64w+16tt .. +16.
static __device__ __forceinline__ void ns_mm(
    const u16* __restrict__ Agh, const u16* __restrict__ Agl,
    u16* AhL, u16* AlL, const u16* BThL, const u16* BTlL,
    int tid, f32x4 acc[4])
{
  const int w = tid>>6, lane = tid&63, g4 = lane>>4, l16 = lane&15;
  const int o0 = (tid>>1)*24 + (tid&1)*8;
  const int o1 = o0 + 4608;           // (tid+384) -> row +192
  const s16x8 z8 = {0,0,0,0,0,0,0,0};
  f32x4 fz = {0.f,0.f,0.f,0.f};
#pragma unroll
  for(int i=0;i<4;i++) acc[i]=fz;
  // prologue: stage chunk 0
  {
    uint4 h0 = *(const uint4*)(Agh + tid*8);
    uint4 h1 = *(const uint4*)(Agh + (384+tid)*8);
    uint4 l0 = *(const uint4*)(Agl + tid*8);
    uint4 l1 = *(const uint4*)(Agl + (384+tid)*8);
    *(uint4*)&AhL[o0] = h0; *(uint4*)&AhL[o1] = h1;
    *(uint4*)&AlL[o0] = l0; *(uint4*)&AlL[o1] = l1;
  }
  __syncthreads();
  for(int c=0;c<24;c++){
    uint4 nh0, nh1, nl0, nl1;
    if(c<23){
      const u16* ph = Agh + (c+1)*6144;
      const u16* pl = Agl + (c+1)*6144;
      nh0 = *(const uint4*)(ph + tid*8);
      nh1 = *(const uint4*)(ph + (384+tid)*8);
      nl0 = *(const uint4*)(pl + tid*8);
      nl1 = *(const uint4*)(pl + (384+tid)*8);
    }
    s16x8 bh = z8, bl = z8;
    if(g4<2){
      bh = *(const s16x8*)&BThL[l16*392 + c*16 + g4*8];
      bl = *(const s16x8*)&BTlL[l16*392 + c*16 + g4*8];
    }
#pragma unroll
    for(int tt=0;tt<4;tt++){
      int rb = 64*w + 16*tt + l16;
      s16x8 ah = z8, al = z8;
      if(g4<2){
        ah = *(const s16x8*)&AhL[rb*24 + g4*8];
        al = *(const s16x8*)&AlL[rb*24 + g4*8];
      }
      acc[tt] = __builtin_amdgcn_mfma_f32_16x16x32_bf16(ah, bh, acc[tt], 0,0,0);
      acc[tt] = __builtin_amdgcn_mfma_f32_16x16x32_bf16(ah, bl, acc[tt], 0,0,0);
      acc[tt] = __builtin_amdgcn_mfma_f32_16x16x32_bf16(al, bh, acc[tt], 0,0,0);
    }
    __syncthreads();
    if(c<23){
      *(uint4*)&AhL[o0] = nh0; *(uint4*)&AhL[o1] = nh1;
      *(uint4*)&AlL[o0] = nl0; *(uint4*)&AlL[o1] = nl1;
      __syncthreads();
    }
  }
}

__global__ __launch_bounds__(384) void nsit_k(u16* __restrict__ XB,
                                              u16* __restrict__ QT,
                                              int it, int niter, int nq)
{
  __shared__ __align__(16) u16 AhL[384*24];
  __shared__ __align__(16) u16 AlL[384*24];
  __shared__ __align__(16) u16 BTh[16*392];
  __shared__ __align__(16) u16 BTl[16*392];
  const int blk = blockIdx.x;
  const int z = blk/24, p = blk - z*24, cp0 = p*16;
  const int tid = threadIdx.x;
  const int w = tid>>6, lane = tid&63, g4 = lane>>4, l16 = lane&15;
  const int rs = it&1, ws2 = rs^1;
  const u16* bin  = XB + (size_t)rs*1179648  + (size_t)z*589824;
  u16*       bout = XB + (size_t)ws2*1179648 + (size_t)z*589824;
  const u16* Xh  = bin;            const u16* Xl  = bin + 147456;
  const u16* Th  = bin + 294912;   const u16* Tl  = bin + 442368;

  // stage BT' = transpose of XcA chunk p:  BT'[n][k] = XcA[p][k][n]
  {
    const u16* sh = Xh + p*6144;
    const u16* sl = Xl + p*6144;
    for(int i=tid; i<768; i+=384){
      int k = i>>1, n0 = (i&1)*8;
      uint4 vh = *(const uint4*)(sh + i*8);
      uint4 vl = *(const uint4*)(sl + i*8);
#pragma unroll
      for(int j=0;j<8;j++){
        BTh[(n0+j)*392 + k] = ((u16*)&vh)[j];
        BTl[(n0+j)*392 + k] = ((u16*)&vl)[j];
      }
    }
  }
  __syncthreads();

  const bool quint = (it < nq);
  f32x4 acc[4], gsv[4];

  // MM1: G_p = XT * Bp
  ns_mm(Th, Tl, AhL, AlL, BTh, BTl, tid, acc);
  if(quint){
#pragma unroll
    for(int tt=0;tt<4;tt++){
      gsv[tt] = acc[tt];
      int m0 = 64*w + 16*tt + g4*4;
      ushort4 h4, l4;
#pragma unroll
      for(int i=0;i<4;i++){
        float v = acc[tt][i];
        u16 hh = f2bf(v);
        ((u16*)&h4)[i]=hh; ((u16*)&l4)[i]=f2bf(v - bf2f(hh));
      }
      *(ushort4*)&BTh[l16*392 + m0] = h4;
      *(ushort4*)&BTl[l16*392 + m0] = l4;
    }
    __syncthreads();
    // MM2: U = X * G
    ns_mm(Xh, Xl, AhL, AlL, BTh, BTl, tid, acc);
#pragma unroll
    for(int tt=0;tt<4;tt++){
      int m0 = 64*w + 16*tt + g4*4;
      ushort4 h4, l4;
#pragma unroll
      for(int i=0;i<4;i++){
        float v = acc[tt][i];
        u16 hh = f2bf(v);
        ((u16*)&h4)[i]=hh; ((u16*)&l4)[i]=f2bf(v - bf2f(hh));
      }
      *(ushort4*)&BTh[l16*392 + m0] = h4;
      *(ushort4*)&BTl[l16*392 + m0] = l4;
    }
    __syncthreads();
    // MM3: T = XT * U  (= G^2 panel)
    ns_mm(Th, Tl, AhL, AlL, BTh, BTl, tid, acc);
    // M = 3.4445 I - 4.7750 G + 2.0315 T
#pragma unroll
    for(int tt=0;tt<4;tt++){
      int m0 = 64*w + 16*tt + g4*4;
      ushort4 h4, l4;
#pragma unroll
      for(int i=0;i<4;i++){
        float v = fmaf(2.0315f, acc[tt][i], -4.7750f*gsv[tt][i])
                + ((m0+i)==(cp0+l16) ? 3.4445f : 0.f);
        u16 hh = f2bf(v);
        ((u16*)&h4)[i]=hh; ((u16*)&l4)[i]=f2bf(v - bf2f(hh));
      }
      *(ushort4*)&BTh[l16*392 + m0] = h4;
      *(ushort4*)&BTl[l16*392 + m0] = l4;
    }
    __syncthreads();
  } else {
    // cubic: M = 1.5 I - 0.5 G
#pragma unroll
    for(int tt=0;tt<4;tt++){
      int m0 = 64*w + 16*tt + g4*4;
      ushort4 h4, l4;
#pragma unroll
      for(int i=0;i<4;i++){
        float v = -0.5f*acc[tt][i] + ((m0+i)==(cp0+l16) ? 1.5f : 0.f);
        u16 hh = f2bf(v);
        ((u16*)&h4)[i]=hh; ((u16*)&l4)[i]=f2bf(v - bf2f(hh));
      }
      *(ushort4*)&BTh[l16*392 + m0] = h4;
      *(ushort4*)&BTl[l16*392 + m0] = l4;
    }
    __syncthreads();
  }
  // MM final: Xn = X * M
  ns_mm(Xh, Xl, AhL, AlL, BTh, BTl, tid, acc);

  if(it == niter-1){
    // QT[z][col][row] = bf16(Q[row][col])
    u16* q = QT + (size_t)z*147456 + (size_t)(cp0+l16)*384;
#pragma unroll
    for(int tt=0;tt<4;tt++){
      int m0 = 64*w + 16*tt + g4*4;
      ushort4 h4;
#pragma unroll
      for(int i=0;i<4;i++) ((u16*)&h4)[i] = f2bf(acc[tt][i]);
      *(ushort4*)&q[m0] = h4;
    }
  } else {
    u16* oXh = bout + p*6144;            u16* oXl = bout + 147456 + p*6144;
    u16* oTh = bout + 294912;            u16* oTl = bout + 442368;
#pragma unroll
    for(int tt=0;tt<4;tt++){
      int m0 = 64*w + 16*tt + g4*4;
      ushort4 h4, l4;
#pragma unroll
      for(int i=0;i<4;i++){
        float v = acc[tt][i];
        u16 hh = f2bf(v);
        ((u16*)&h4)[i]=hh; ((u16*)&l4)[i]=f2bf(v - bf2f(hh));
        oXh[(m0+i)*16 + l16] = hh;
        oXl[(m0+i)*16 + l16] = ((u16*)&l4)[i];
      }
      // XTcA'[4w+tt][cp0+l16][g4*4 .. +3]
      size_t to = (size_t)(4*w+tt)*6144 + (size_t)(cp0+l16)*16 + g4*4;
      *(ushort4*)&oTh[to] = h4;
      *(ushort4*)&oTl[to] = l4;
    }
  }
}

// ---------------- host-side orchestration ----------------
extern "C" void kernel_launch(void* const* d_in, const int* in_sizes, int n_in,
                              void* d_out, int out_size, void* d_ws, size_t ws_size,
                              hipStream_t stream)
{
  const float* x      = (const float*)d_in[0];
  const float* Wq     = (const float*)d_in[1];
  const float* Wk     = (const float*)d_in[2];
  const float* Wv     = (const float*)d_in[3];
  const float* Wp     = (const float*)d_in[4];
  const float* bp     = (const float*)d_in[5];
  const float* scale1 = (const float*)d_in[6];
  const float* scale2 = (const float*)d_in[7];
  const float* W1     = (const float*)d_in[8];
  const float* b1     = (const float*)d_in[9];
  const float* W2     = (const float*)d_in[10];
  const float* b2     = (const float*)d_in[11];
  const float* Wo_in  = (const float*)d_in[12];
  const float* Wo_out = (const float*)d_in[13];

  // ---- workspace layout ----
  char* ws = (char*)d_ws;
  u16* XB   = (u16*)(ws + 0);                 // NS X buffers: 2 sets x (2z x 4 matrices) = 4718592 B
  u16* Wqkv = (u16*)(ws + 4719104L);          // [h][{q,k,v}][64][384] bf16
  u16* WpT  = (u16*)(ws + 5603840L);          // [384][384]
  u16* W1T  = (u16*)(ws + 5898752L);          // [307][384]
  u16* W2T  = (u16*)(ws + 6134528L);          // [384][320] (k-padded with zeros)
  u16* QT   = (u16*)(ws + 6380288L);          // orth(Wo_in)^T, orth(Wo_out)^T bf16 (589824 B)
  float* part = (float*)(ws + 6970112L);      // 48 floats
  float* invb = (float*)(ws + 6970496L);      // 2 floats
  u16* h1b  = (u16*)(ws + 8388608L);          // S0: h1 -> h6                (48 MB)
  u16* qkvb = (u16*)(ws + 58720256L);         // S1-S3: qkv packed -> h2/h3/h4 (144 MB)
  u16* atb  = (u16*)(ws + 209715200L);        // S4: attn_cat -> h5 [65536][320]
  u16* h2b = qkvb;
  u16* h3b = qkvb + 25165824L;
  u16* h4b = qkvb + 50331648L;
  u16* h5b = atb;
  u16* h6b = h1b;

  // --- weight transpose+cast ---
  tcast_k<<<dim3(12, 2,6),256,0,stream>>>(Wq,24576L, Wqkv,        73728L, 384, 64,384);
  tcast_k<<<dim3(12, 2,6),256,0,stream>>>(Wk,24576L, Wqkv+24576L, 73728L, 384, 64,384);
  tcast_k<<<dim3(12, 2,6),256,0,stream>>>(Wv,24576L, Wqkv+49152L, 73728L, 384, 64,384);
  tcast_k<<<dim3(12,12,1),256,0,stream>>>(Wp,0L,     WpT,0L,     384,384,384);
  tcast_k<<<dim3(12,10,1),256,0,stream>>>(W1,0L,     W1T,0L,     384,307,384);
  tcast_k<<<dim3(10,12,1),256,0,stream>>>(W2,0L,     W2T,0L,     307,384,320);

  // --- orth via stream-ordered Newton-Schulz chain (10 quintic + 5 cubic) ---
  const int NITER = 15, NQ = 10;
  fpart_k<<<48,256,0,stream>>>(Wo_in, Wo_out, part);
  fcomb_k<<<1,64,0,stream>>>(part, invb);
  nsinit_k<<<48,256,0,stream>>>(Wo_in, Wo_out, invb, XB);
  for(int it=0; it<NITER; ++it)
    nsit_k<<<48,384,0,stream>>>(XB, QT, it, NITER, NQ);

  // --- main path: bf16 activations + MFMA throughout ---
  rms_k<float,u16><<<16384,256,0,stream>>>(x, scale1, h1b);
  mgemm_k<u16,float><<<dim3(512,1,18),256,0,stream>>>(
      h1b,384,0L,  Wqkv,384,24576L,
      qkvb,16384L,294912L,64,  (const float*)nullptr,0L, nullptr,
      65536,64,64,384, 0.f,0);
  mattn_k<<<1536,256,0,stream>>>(qkvb, atb);
  mgemm_k<u16,u16><<<dim3(512,6,1),256,0,stream>>>(
      atb,384,0L,  WpT,384,0L,
      h2b,0L,98304L,384,  h1b,0L, bp,
      65536,384,384,384, 1.f,0);
  rms_k<u16,u16><<<16384,256,0,stream>>>(h2b, scale2, h3b);
  mgemm_k<u16,float><<<dim3(512,6,1),256,0,stream>>>(
      h3b,384,0L,  QT,384,0L,
      h4b,0L,98304L,384,  (const float*)nullptr,0L, nullptr,
      65536,384,384,384, 0.f,0);
  mgemm_k<u16,float><<<dim3(512,5,1),256,0,stream>>>(
      h4b,384,0L,  W1T,384,0L,
      h5b,0L,81920L,320,  (const float*)nullptr,0L, b1,
      65536,307,320,384, 0.f,1);
  mgemm_k<u16,float><<<dim3(512,6,1),256,0,stream>>>(
      h5b,320,0L,  W2T,320,0L,
      h6b,0L,98304L,384,  (const float*)nullptr,0L, b2,
      65536,384,384,320, 0.f,0);
  mgemm_k<float,u16><<<dim3(512,6,1),256,0,stream>>>(
      h6b,384,0L,  QT+147456,384,0L,
      (float*)d_out,0L,98304L,384,  h6b,0L, nullptr,
      65536,384,384,384, 1.f,0);

  (void)in_sizes; (void)n_in; (void)ws_size; (void)out_size;
}